// Round 9
// baseline (211.534 us; speedup 1.0000x reference)
//
#include <hip/hip_runtime.h>

#define NN 192

// Stateless scheme: thread = (lane -> x-triple, wave -> y, block.y -> z).
// Loads its full 3x3x2 row neighborhood (wave-uniform row offsets), folds:
//   p = z-box, q = z-diff  (per y-plane)
//   S = y-box(p), D = y-diff(p), T = y-box(q)
//   Gx = x-diff(S), Gy = x-box(D), Gz = x-box(T)   (x via lane shuffles)
// Raw (un-halved) gradients: the 0.5^2 factors cancel when EPS^2 -> 4*EPS^2.
// No barriers, no cross-iteration state: latency hidden by TLP (36864 waves).

__device__ __forceinline__ float3 ld3(const float* p) { return *(const float3*)p; }

__device__ __forceinline__ void grads(const float* __restrict__ Ab,
                                      const int zr[3], const int yo[3],
                                      int lane, float G[3][3]) {
    float p[3][3], q[3][3];
#pragma unroll
    for (int yy = 0; yy < 3; ++yy) {
        const float3 a = ld3(Ab + zr[0] + yo[yy]);
        const float3 b = ld3(Ab + zr[1] + yo[yy]);
        const float3 c = ld3(Ab + zr[2] + yo[yy]);
        p[yy][0] = a.x + b.x + c.x;  q[yy][0] = c.x - a.x;
        p[yy][1] = a.y + b.y + c.y;  q[yy][1] = c.y - a.y;
        p[yy][2] = a.z + b.z + c.z;  q[yy][2] = c.z - a.z;
    }
    float S[3], D[3], T[3];
#pragma unroll
    for (int i = 0; i < 3; ++i) {
        S[i] = p[0][i] + p[1][i] + p[2][i];
        D[i] = p[2][i] - p[0][i];
        T[i] = q[0][i] + q[1][i] + q[2][i];
    }
    float SL = __shfl_up(S[2], 1, 64), SR = __shfl_down(S[0], 1, 64);
    float DL = __shfl_up(D[2], 1, 64), DR = __shfl_down(D[0], 1, 64);
    float TL = __shfl_up(T[2], 1, 64), TR = __shfl_down(T[0], 1, 64);
    if (lane == 0)  { SL = S[0]; DL = D[0]; TL = T[0]; }   // clamp x=-1 -> 0
    if (lane == 63) { SR = S[2]; DR = D[2]; TR = T[2]; }   // clamp x=192 -> 191
    G[0][0] = S[1] - SL;           G[0][1] = S[2] - S[0];        G[0][2] = SR - S[1];
    G[1][0] = DL + D[0] + D[1];    G[1][1] = D[0] + D[1] + D[2]; G[1][2] = D[1] + D[2] + DR;
    G[2][0] = TL + T[0] + T[1];    G[2][1] = T[0] + T[1] + T[2]; G[2][2] = T[1] + T[2] + TR;
}

__global__ __launch_bounds__(256, 4) void ngf_kernel(const float* __restrict__ I,
                                                     const float* __restrict__ J,
                                                     const float* __restrict__ M,
                                                     float* __restrict__ out) {
    const int lane = threadIdx.x;               // 0..63 -> x = 3*lane ..
    const int wy = threadIdx.y;                 // 0..3
    const int z = blockIdx.y;
    const int y = blockIdx.x * 4 + wy;

    const int zm = (z == 0) ? 0 : z - 1;
    const int zp = (z == NN - 1) ? (NN - 1) : z + 1;
    const int ym = (y == 0) ? 0 : y - 1;
    const int yp = (y == NN - 1) ? (NN - 1) : y + 1;

    const int zr[3] = {zm * NN * NN, z * NN * NN, zp * NN * NN};
    const int yo[3] = {ym * NN, y * NN, yp * NN};

    const int xoff = lane * 3;
    const float3 m3 = ld3(M + zr[1] + yo[1] + xoff);

    float GI[3][3], GJ[3][3];
    grads(I + xoff, zr, yo, lane, GI);
    grads(J + xoff, zr, yo, lane, GJ);

    const float mm[3] = {m3.x, m3.y, m3.z};
    float acc = 0.0f;
#pragma unroll
    for (int i = 0; i < 3; ++i) {
        const float Ix = GI[0][i], Iy = GI[1][i], Iz = GI[2][i];
        const float Jx = GJ[0][i], Jy = GJ[1][i], Jz = GJ[2][i];
        const float im = Ix * Ix + Iy * Iy + Iz * Iz + 0.04f;
        const float jm = Jx * Jx + Jy * Jy + Jz * Jz + 0.04f;
        const float dot = Ix * Jx + Iy * Jy + Iz * Jz;
        acc += (1.0f - dot * dot * __builtin_amdgcn_rcpf(im * jm)) * mm[i];
    }

    // mean scaling, then wave -> block -> global reduction
    acc *= (1.0f / ((float)NN * (float)NN * (float)NN));
#pragma unroll
    for (int off = 32; off > 0; off >>= 1)
        acc += __shfl_down(acc, off, 64);

    __shared__ float red[4];
    if (lane == 0) red[wy] = acc;
    __syncthreads();
    if (wy == 0 && lane == 0)
        atomicAdd(out, (red[0] + red[1]) + (red[2] + red[3]));
}

extern "C" void kernel_launch(void* const* d_in, const int* in_sizes, int n_in,
                              void* d_out, int out_size, void* d_ws, size_t ws_size,
                              hipStream_t stream) {
    const float* I = (const float*)d_in[0];
    const float* J = (const float*)d_in[1];
    const float* M = (const float*)d_in[2];
    float* out = (float*)d_out;

    hipMemsetAsync(d_out, 0, sizeof(float), stream);

    dim3 block(64, 4);                 // 256 threads = 4 waves (4 consecutive y)
    dim3 grid(NN / 4, NN);             // (48, 192) = 9216 blocks
    ngf_kernel<<<grid, block, 0, stream>>>(I, J, M, out);
}

// Round 10
// 118.533 us; speedup vs baseline: 1.7846x; 1.7846x over previous
//
#include <hip/hip_runtime.h>

#define NN 192
#define BZ 4
#define YC 8
#define NTHR (64 * BZ)
#define NPART ((NN / YC) * (NN / BZ))   // 1152 block partials

// x mapped across the 64 lanes of a wave, 3 floats/lane (192 = 64*3).
// z-fold-first: fold the z-triple into p = z-box, q = z-diff per (x,y); then
//   Gx = S(x+1)-S(x-1),      S = y-box of p
//   Gy = D(x-1)+D(x)+D(x+1), D = y-diff of p
//   Gz = T(x-1)+T(x)+T(x+1), T = y-box of q
// x-halo of p/q via lane shuffles, kept in 5-wide extended slots.
// Raw (un-halved) gradients: 0.5^2 factors cancel when EPS^2 -> 4*EPS^2 = 0.04.
// Reduction: NO contended atomic (measured ~10 ns/op serialization) —
// per-block partial to d_ws, then a tiny second kernel sums them.

__device__ __forceinline__ void fold_pq(const float3 rm, const float3 r0, const float3 rp,
                                        int lane, float pe[5], float qe[5]) {
    const float p0 = rm.x + r0.x + rp.x;
    const float p1 = rm.y + r0.y + rp.y;
    const float p2 = rm.z + r0.z + rp.z;
    const float q0 = rp.x - rm.x;
    const float q1 = rp.y - rm.y;
    const float q2 = rp.z - rm.z;
    float pL = __shfl_up(p2, 1, 64);
    float pR = __shfl_down(p0, 1, 64);
    float qL = __shfl_up(q2, 1, 64);
    float qR = __shfl_down(q0, 1, 64);
    if (lane == 0)  { pL = p0; qL = q0; }   // clamp x=-1 -> 0
    if (lane == 63) { pR = p2; qR = q2; }   // clamp x=192 -> 191
    pe[0] = pL; pe[1] = p0; pe[2] = p1; pe[3] = p2; pe[4] = pR;
    qe[0] = qL; qe[1] = q0; qe[2] = q1; qe[3] = q2; qe[4] = qR;
}

__device__ __forceinline__ void load_plane(const float* const base[6], int yrow,
                                           float3 rI[3], float3 rJ[3]) {
#pragma unroll
    for (int d = 0; d < 3; ++d) rI[d] = *reinterpret_cast<const float3*>(base[d] + yrow);
#pragma unroll
    for (int d = 0; d < 3; ++d) rJ[d] = *reinterpret_cast<const float3*>(base[3 + d] + yrow);
}

__global__ __launch_bounds__(NTHR, 3) void ngf_kernel(const float* __restrict__ I,
                                                      const float* __restrict__ J,
                                                      const float* __restrict__ M,
                                                      float* __restrict__ ws) {
    const int lane = threadIdx.x;         // 0..63
    const int tz = threadIdx.y;
    const int xoff = lane * 3;
    const int z = blockIdx.y * BZ + tz;
    const int ybase = blockIdx.x * YC;

    const int gzm = (z == 0) ? 0 : z - 1;
    const int gzp = (z == NN - 1) ? (NN - 1) : z + 1;

    const float* base[6] = {
        I + gzm * NN * NN + xoff, I + z * NN * NN + xoff, I + gzp * NN * NN + xoff,
        J + gzm * NN * NN + xoff, J + z * NN * NN + xoff, J + gzp * NN * NN + xoff};
    const float* mbase = M + z * NN * NN + xoff;

    float pe[2][3][5], qe[2][3][5];       // rotating slots [array][slot][5]

    // seed: fold plane y=ybase-1 (clamped) -> slot 0, y=ybase -> slot 1
    {
        float3 rI[3], rJ[3];
        load_plane(base, ((ybase == 0) ? 0 : (ybase - 1)) * NN, rI, rJ);
        fold_pq(rI[0], rI[1], rI[2], lane, pe[0][0], qe[0][0]);
        fold_pq(rJ[0], rJ[1], rJ[2], lane, pe[1][0], qe[1][0]);
        load_plane(base, ybase * NN, rI, rJ);
        fold_pq(rI[0], rI[1], rI[2], lane, pe[0][1], qe[0][1]);
        fold_pq(rJ[0], rJ[1], rJ[2], lane, pe[1][1], qe[1][1]);
    }

    // raw-plane double buffer; prefetch plane ybase+1 (<= 185 < 192)
    float3 bI[2][3], bJ[2][3];
    load_plane(base, (ybase + 1) * NN, bI[0], bJ[0]);
    float3 mcur = *reinterpret_cast<const float3*>(mbase + ybase * NN);

    float acc = 0.0f;
#pragma unroll
    for (int yy = 0; yy < YC; ++yy) {
        const int cb = yy & 1, nb = cb ^ 1;   // constant after unroll

        // 1) issue next plane's loads (consumed next iteration)
        float3 mnxt = mcur;
        if (yy < YC - 1) {
            int gy = ybase + yy + 2;
            gy = (gy > NN - 1) ? (NN - 1) : gy;
            load_plane(base, gy * NN, bI[nb], bJ[nb]);
            mnxt = *reinterpret_cast<const float3*>(mbase + (ybase + yy + 1) * NN);
        }

        // 2) fold plane y = ybase+yy+1 (loads issued one step ago) -> slot sC
        const int sC = (yy + 2) % 3;
        fold_pq(bI[cb][0], bI[cb][1], bI[cb][2], lane, pe[0][sC], qe[0][sC]);
        fold_pq(bJ[cb][0], bJ[cb][1], bJ[cb][2], lane, pe[1][sC], qe[1][sC]);

        // 3) NGF at y = ybase+yy (slots s0=y-1, s1=y, sC=y+1)
        const int s0 = yy % 3, s1 = (yy + 1) % 3;
        float G[2][3][3];
#pragma unroll
        for (int ar = 0; ar < 2; ++ar) {
            float S[5], D[5], T[5];
#pragma unroll
            for (int i = 0; i < 5; ++i) {
                S[i] = pe[ar][s0][i] + pe[ar][s1][i] + pe[ar][sC][i];
                D[i] = pe[ar][sC][i] - pe[ar][s0][i];
                T[i] = qe[ar][s0][i] + qe[ar][s1][i] + qe[ar][sC][i];
            }
#pragma unroll
            for (int i = 0; i < 3; ++i) {
                G[ar][0][i] = S[i + 2] - S[i];
                G[ar][1][i] = D[i] + D[i + 1] + D[i + 2];
                G[ar][2][i] = T[i] + T[i + 1] + T[i + 2];
            }
        }
        const float mm[3] = {mcur.x, mcur.y, mcur.z};
#pragma unroll
        for (int i = 0; i < 3; ++i) {
            const float Ix = G[0][0][i], Iy = G[0][1][i], Iz = G[0][2][i];
            const float Jx = G[1][0][i], Jy = G[1][1][i], Jz = G[1][2][i];
            const float im = Ix * Ix + Iy * Iy + Iz * Iz + 0.04f;
            const float jm = Jx * Jx + Jy * Jy + Jz * Jz + 0.04f;
            const float dot = Ix * Jx + Iy * Jy + Iz * Jz;
            acc += (1.0f - dot * dot * __builtin_amdgcn_rcpf(im * jm)) * mm[i];
        }
        mcur = mnxt;
    }

    // mean scaling, then wave -> block partial (NO global atomic)
    acc *= (1.0f / ((float)NN * (float)NN * (float)NN));
#pragma unroll
    for (int off = 32; off > 0; off >>= 1)
        acc += __shfl_down(acc, off, 64);

    __shared__ float red[NTHR / 64];
    const int flat = tz * 64 + lane;
    if ((flat & 63) == 0) red[flat >> 6] = acc;
    __syncthreads();
    if (flat == 0) {
        float s = 0.0f;
#pragma unroll
        for (int w = 0; w < NTHR / 64; ++w) s += red[w];
        ws[blockIdx.y * gridDim.x + blockIdx.x] = s;
    }
}

__global__ __launch_bounds__(256) void reduce_kernel(const float* __restrict__ ws,
                                                     float* __restrict__ out) {
    float s = 0.0f;
    for (int i = threadIdx.x; i < NPART; i += 256) s += ws[i];
#pragma unroll
    for (int off = 32; off > 0; off >>= 1)
        s += __shfl_down(s, off, 64);
    __shared__ float red[4];
    if ((threadIdx.x & 63) == 0) red[threadIdx.x >> 6] = s;
    __syncthreads();
    if (threadIdx.x == 0) out[0] = (red[0] + red[1]) + (red[2] + red[3]);
}

extern "C" void kernel_launch(void* const* d_in, const int* in_sizes, int n_in,
                              void* d_out, int out_size, void* d_ws, size_t ws_size,
                              hipStream_t stream) {
    const float* I = (const float*)d_in[0];
    const float* J = (const float*)d_in[1];
    const float* M = (const float*)d_in[2];
    float* out = (float*)d_out;
    float* ws = (float*)d_ws;

    dim3 block(64, BZ);               // 256 threads = 4 waves
    dim3 grid(NN / YC, NN / BZ);      // (24, 48) = 1152 blocks
    ngf_kernel<<<grid, block, 0, stream>>>(I, J, M, ws);
    reduce_kernel<<<1, 256, 0, stream>>>(ws, out);
}